// Round 8
// baseline (200.236 us; speedup 1.0000x reference)
//
#include <hip/hip_runtime.h>

#define NPOLY 256
#define VPP   64
#define LCH   32
#define NV    (1 + NPOLY * VPP)
#define LN_EPS 1e-5f

typedef __bf16 bf16x8 __attribute__((ext_vector_type(8)));
typedef float  f32x4  __attribute__((ext_vector_type(4)));

union U4B8 { uint4 u; bf16x8 v; };

// hardware RNE pack: lo=bf16(a), hi=bf16(b)
__device__ __forceinline__ unsigned packbf(float a, float b) {
    unsigned r;
    asm("v_cvt_pk_bf16_f32 %0, %1, %2" : "=v"(r) : "v"(a), "v"(b));
    return r;
}

// DPP cross-lane term (VALU-only, fuses to v_add_f32_dpp; no DS op, no lgkmcnt)
#define DPPF(x, ctrl) __int_as_float(__builtin_amdgcn_update_dpp(0, __float_as_int(x), (ctrl), 0xF, 0xF, true))

// 16-lane butterfly sum (bitwise == __shfl_xor 1/2/4/8 tree)
__device__ __forceinline__ float red16sum(float x) {
    x += DPPF(x, 0xB1);
    x += DPPF(x, 0x4E);
    x += DPPF(x, 0x141);
    x += DPPF(x, 0x140);
    return x;
}

// ---------------------------------------------------------------------------
// vn_prep: coalesced folds + 42 bf16 B-fragments:
//  f0-1  : W0 (rows 0..31)            f2-5  : W1 top (rows 0..31)
//  f6-21 : W2 top (rows 0..63)        f22-25: W1 bottom (rows 32..63)
//  f26-41: W2 bottom (rows 64..127)
// frag f, lane L: 8 bf16 = W[k0+j][ct*16+(L&15)], k0 = base + (L>>4)*8
// ---------------------------------------------------------------------------
__global__ void vn_prep(const float* __restrict__ W0, const float* __restrict__ W1,
                        const float* __restrict__ W2,
                        const float* __restrict__ Wq, const float* __restrict__ Wk,
                        const float* __restrict__ Wv,
                        float* __restrict__ Wvf, float* __restrict__ Wqf,
                        float* __restrict__ WkfT, uint4* __restrict__ wpack)
{
    int t = blockIdx.x * 256 + threadIdx.x;
    if (t < 32768) {                     // Wv fold
        Wvf[t] = Wv[t] + Wv[t + 32768];
        return;
    }
    t -= 32768;
    if (t < 32768) {                     // Wq fold
        Wqf[t] = Wq[t] + Wq[t + 32768];
        return;
    }
    t -= 32768;
    if (t < 32768) {                     // Wk fold + transpose
        int j = t >> 8, c = t & 255;
        WkfT[c * 128 + j] = Wk[j * 256 + c] + Wk[(j + 128) * 256 + c];
        return;
    }
    t -= 32768;
    if (t < 42 * 64) {                   // wpack
        int f = t >> 6, L = t & 63, q = L >> 4, m = L & 15;
        const float* src; int N, k0, col;
        if (f < 2)       { src = W0; N = 32;  k0 = q * 8;            col = f * 16 + m; }
        else if (f < 6)  { src = W1; N = 64;  k0 = q * 8;            col = (f - 2) * 16 + m; }
        else if (f < 22) { int g = f - 6;  src = W2; N = 128; k0 = (g >> 3) * 32 + q * 8;      col = (g & 7) * 16 + m; }
        else if (f < 26) { src = W1; N = 64;  k0 = 32 + q * 8;       col = (f - 22) * 16 + m; }
        else             { int g = f - 26; src = W2; N = 128; k0 = 64 + (g >> 3) * 32 + q * 8; col = (g & 7) * 16 + m; }
        float e[8];
        #pragma unroll
        for (int j = 0; j < 8; j++) e[j] = src[(k0 + j) * N + col];
        uint4 o;
        o.x = packbf(e[0], e[1]); o.y = packbf(e[2], e[3]);
        o.z = packbf(e[4], e[5]); o.w = packbf(e[6], e[7]);
        wpack[f * 64 + L] = o;
    }
}

// ---------------------------------------------------------------------------
// vn_mlp: ONE POLY PER 256-THREAD BLOCK, 4 waves x 16 rows each.
// New: uniform-concat (au) terms moved onto the matrix pipe via row-uniform
// agg A-fragments chained into the MFMA C-operand:
//   acc = mfma(A_h, W_top, mfma(A_agg, W_bot, bias))
// Deletes au1/au2 VALU loops + W1/W2 global reads + 2 barriers.
// Buffers: partA = l0 colmax then l2 colmax; partB = l1 colmax.
// hbuf rows are wave-owned -> intra-wave DS ordering, no cross-wave sync.
// ---------------------------------------------------------------------------
__global__ __launch_bounds__(256, 3) void vn_mlp(
    const float* __restrict__ data, const uint4* __restrict__ wpack,
    const float* __restrict__ b0, const float* __restrict__ g0, const float* __restrict__ be0,
    const float* __restrict__ b1, const float* __restrict__ g1, const float* __restrict__ be1,
    const float* __restrict__ b2, const float* __restrict__ g2, const float* __restrict__ be2,
    float* __restrict__ Ph)
{
    __shared__ __align__(16) unsigned short hbuf[64 * 72];  // 9216 B (rows wave-owned)
    __shared__ float partA[4][128];   // l0 colmax (32) -> l2 colmax (128)
    __shared__ float partB[4][64];    // l1 colmax

    const int tid = threadIdx.x;
    const int w = tid >> 6, L = tid & 63, q = L >> 4, m = L & 15;
    const int blk = blockIdx.x;
    const int bb = blk >> 8, pp = blk & 255;
    const int r0 = w * 16;            // this wave's row base

    // ---------------- layer 0 : 32 -> 32 (rows r0..r0+15) ----------------
    const float* rowbase = data + ((size_t)bb * NV + 1 + (size_t)pp * VPP) * LCH;
    bf16x8 A0;
    {
        const float* rp = rowbase + (size_t)(r0 + m) * LCH + q * 8;
        float4 u = *(const float4*)rp;
        float4 v = *(const float4*)(rp + 4);
        if (q == 3) v.w = 0.f;                 // vecs[:, :, -1] = 0
        U4B8 c;
        c.u.x = packbf(u.x, u.y); c.u.y = packbf(u.z, u.w);
        c.u.z = packbf(v.x, v.y); c.u.w = packbf(v.z, v.w);
        A0 = c.v;
    }
    f32x4 acc0[2];
    {
        U4B8 t0, t1; t0.u = wpack[0 * 64 + L]; t1.u = wpack[1 * 64 + L];
        float bca = b0[m], bcb = b0[16 + m];
        f32x4 a0 = { bca, bca, bca, bca };
        f32x4 a1 = { bcb, bcb, bcb, bcb };
        acc0[0] = __builtin_amdgcn_mfma_f32_16x16x32_bf16(A0, t0.v, a0, 0, 0, 0);
        acc0[1] = __builtin_amdgcn_mfma_f32_16x16x32_bf16(A0, t1.v, a1, 0, 0, 0);
    }
    // LN (per row, N=32) + relu + wave-partial col-max
    {
        float g0c[2]  = { g0[m],  g0[16 + m]  };
        float be0c[2] = { be0[m], be0[16 + m] };
        float a0mx[2] = { 0.f, 0.f };
        #pragma unroll
        for (int reg = 0; reg < 4; reg++) {
            float x0 = acc0[0][reg], x1 = acc0[1][reg];
            float rs = red16sum(x0 + x1);
            float rq = red16sum(x0 * x0 + x1 * x1);
            float mu = rs * (1.f / 32.f);
            float var = rq * (1.f / 32.f) - mu * mu;
            float ri = rsqrtf(var + LN_EPS);
            #pragma unroll
            for (int ct = 0; ct < 2; ct++) {
                float v = fmaxf(fmaf(g0c[ct] * ri, acc0[ct][reg] - mu, be0c[ct]), 0.f);
                acc0[ct][reg] = v;
                a0mx[ct] = fmaxf(a0mx[ct], v);
            }
        }
        #pragma unroll
        for (int ct = 0; ct < 2; ct++) {
            float v = a0mx[ct];
            v = fmaxf(v, __shfl_xor(v, 16, 64));
            v = fmaxf(v, __shfl_xor(v, 32, 64));
            a0mx[ct] = v;
        }
        if (q == 0) { partA[w][m] = a0mx[0]; partA[w][16 + m] = a0mx[1]; }
    }
    // stage h0 (bf16), wave-local rows
    #pragma unroll
    for (int reg = 0; reg < 4; reg++) {
        int row = r0 + q * 4 + reg;
        unsigned u = packbf(acc0[0][reg], acc0[1][reg]);
        hbuf[row * 72 + m]      = (unsigned short)u;
        hbuf[row * 72 + 16 + m] = (unsigned short)(u >> 16);
    }
    __syncthreads();   // B1: partA(l0 colmax) ready

    // ---------------- layer 1 : concat(h0, agg0) @ W1 ----------------
    // A_agg0: every row = agg0; lane (q,m) holds agg0[q*8+j] (broadcast reads)
    bf16x8 Ag0;
    {
        float e[8];
        #pragma unroll
        for (int j = 0; j < 8; j++) {
            int k = q * 8 + j;
            e[j] = fmaxf(fmaxf(partA[0][k], partA[1][k]), fmaxf(partA[2][k], partA[3][k]));
        }
        U4B8 c;
        c.u.x = packbf(e[0], e[1]); c.u.y = packbf(e[2], e[3]);
        c.u.z = packbf(e[4], e[5]); c.u.w = packbf(e[6], e[7]);
        Ag0 = c.v;
    }
    bf16x8 A1;
    { U4B8 c; c.u = *(const uint4*)(hbuf + (r0 + m) * 72 + q * 8); A1 = c.v; }
    f32x4 acc1[4];
    #pragma unroll
    for (int ct = 0; ct < 4; ct++) {
        U4B8 wt, wbt;
        wt.u  = wpack[(2 + ct) * 64 + L];    // W1 rows 0..31
        wbt.u = wpack[(22 + ct) * 64 + L];   // W1 rows 32..63
        float bb1 = b1[ct * 16 + m];
        f32x4 a = { bb1, bb1, bb1, bb1 };
        a = __builtin_amdgcn_mfma_f32_16x16x32_bf16(Ag0, wbt.v, a, 0, 0, 0);
        acc1[ct] = __builtin_amdgcn_mfma_f32_16x16x32_bf16(A1, wt.v, a, 0, 0, 0);
    }
    float a1mx[4] = { 0.f, 0.f, 0.f, 0.f };
    {
        float g1c[4], be1c[4];
        #pragma unroll
        for (int ct = 0; ct < 4; ct++) { g1c[ct] = g1[ct * 16 + m]; be1c[ct] = be1[ct * 16 + m]; }
        #pragma unroll
        for (int reg = 0; reg < 4; reg++) {
            float rs = 0.f, rq = 0.f;
            #pragma unroll
            for (int ct = 0; ct < 4; ct++) { float x = acc1[ct][reg]; rs += x; rq = fmaf(x, x, rq); }
            rs = red16sum(rs);
            rq = red16sum(rq);
            float mu = rs * (1.f / 64.f);
            float var = rq * (1.f / 64.f) - mu * mu;
            float ri = rsqrtf(var + LN_EPS);
            #pragma unroll
            for (int ct = 0; ct < 4; ct++) {
                float v = fmaxf(fmaf(g1c[ct] * ri, acc1[ct][reg] - mu, be1c[ct]), 0.f);
                acc1[ct][reg] = v;
                a1mx[ct] = fmaxf(a1mx[ct], v);
            }
        }
        #pragma unroll
        for (int ct = 0; ct < 4; ct++) {
            float v = a1mx[ct];
            v = fmaxf(v, __shfl_xor(v, 16, 64));
            v = fmaxf(v, __shfl_xor(v, 32, 64));
            a1mx[ct] = v;
        }
    }
    // l1 colmax -> partB (fresh buffer: no WAR with partA's Ag0 readers)
    if (q == 0) {
        #pragma unroll
        for (int ct = 0; ct < 4; ct++) partB[w][ct * 16 + m] = a1mx[ct];
    }
    // stage h1 (bf16), wave-local rows (A1 already read; intra-wave order ok)
    #pragma unroll
    for (int reg = 0; reg < 4; reg++) {
        int row = r0 + q * 4 + reg;
        unsigned ua = packbf(acc1[0][reg], acc1[1][reg]);
        unsigned ub = packbf(acc1[2][reg], acc1[3][reg]);
        hbuf[row * 72 + m]      = (unsigned short)ua;
        hbuf[row * 72 + 16 + m] = (unsigned short)(ua >> 16);
        hbuf[row * 72 + 32 + m] = (unsigned short)ub;
        hbuf[row * 72 + 48 + m] = (unsigned short)(ub >> 16);
    }
    __syncthreads();   // B2: partB(l1 colmax) ready; all Ag0 readers done

    // ---------------- layer 2 : concat(h1, agg1) @ W2 ----------------
    bf16x8 Ag1a, Ag1b;
    {
        float e[8], e2[8];
        #pragma unroll
        for (int j = 0; j < 8; j++) {
            int k = q * 8 + j;
            e[j]  = fmaxf(fmaxf(partB[0][k], partB[1][k]), fmaxf(partB[2][k], partB[3][k]));
            int k2 = 32 + k;
            e2[j] = fmaxf(fmaxf(partB[0][k2], partB[1][k2]), fmaxf(partB[2][k2], partB[3][k2]));
        }
        U4B8 c, d;
        c.u.x = packbf(e[0], e[1]);  c.u.y = packbf(e[2], e[3]);
        c.u.z = packbf(e[4], e[5]);  c.u.w = packbf(e[6], e[7]);
        d.u.x = packbf(e2[0], e2[1]); d.u.y = packbf(e2[2], e2[3]);
        d.u.z = packbf(e2[4], e2[5]); d.u.w = packbf(e2[6], e2[7]);
        Ag1a = c.v; Ag1b = d.v;
    }
    bf16x8 A2[2];
    #pragma unroll
    for (int ks = 0; ks < 2; ks++) {
        U4B8 c; c.u = *(const uint4*)(hbuf + (r0 + m) * 72 + ks * 32 + q * 8);
        A2[ks] = c.v;
    }
    f32x4 acc2[8];
    #pragma unroll
    for (int ct = 0; ct < 8; ct++) {
        U4B8 wa, wb, wc, wd;
        wa.u = wpack[(6 + ct) * 64 + L];     // W2 rows  0..31
        wb.u = wpack[(14 + ct) * 64 + L];    // W2 rows 32..63
        wc.u = wpack[(26 + ct) * 64 + L];    // W2 rows 64..95
        wd.u = wpack[(34 + ct) * 64 + L];    // W2 rows 96..127
        float bb2 = b2[ct * 16 + m];
        f32x4 a = { bb2, bb2, bb2, bb2 };
        a = __builtin_amdgcn_mfma_f32_16x16x32_bf16(Ag1a, wc.v, a, 0, 0, 0);
        a = __builtin_amdgcn_mfma_f32_16x16x32_bf16(Ag1b, wd.v, a, 0, 0, 0);
        a = __builtin_amdgcn_mfma_f32_16x16x32_bf16(A2[0], wa.v, a, 0, 0, 0);
        a = __builtin_amdgcn_mfma_f32_16x16x32_bf16(A2[1], wb.v, a, 0, 0, 0);
        acc2[ct] = a;
    }
    {
        float g2c[8], be2c[8];
        #pragma unroll
        for (int ct = 0; ct < 8; ct++) { g2c[ct] = g2[ct * 16 + m]; be2c[ct] = be2[ct * 16 + m]; }
        float m2[8] = { 0.f, 0.f, 0.f, 0.f, 0.f, 0.f, 0.f, 0.f };
        #pragma unroll
        for (int reg = 0; reg < 4; reg++) {
            float rs = 0.f, rq = 0.f;
            #pragma unroll
            for (int ct = 0; ct < 8; ct++) { float x = acc2[ct][reg]; rs += x; rq = fmaf(x, x, rq); }
            rs = red16sum(rs);
            rq = red16sum(rq);
            float mu = rs * (1.f / 128.f);
            float var = rq * (1.f / 128.f) - mu * mu;
            float ri = rsqrtf(var + LN_EPS);
            #pragma unroll
            for (int ct = 0; ct < 8; ct++) {
                float v = fmaxf(fmaf(g2c[ct] * ri, acc2[ct][reg] - mu, be2c[ct]), 0.f);
                m2[ct] = fmaxf(m2[ct], v);
            }
        }
        #pragma unroll
        for (int ct = 0; ct < 8; ct++) {
            float v = m2[ct];
            v = fmaxf(v, __shfl_xor(v, 16, 64));
            v = fmaxf(v, __shfl_xor(v, 32, 64));
            m2[ct] = v;
        }
        if (q == 0) {
            #pragma unroll
            for (int ct = 0; ct < 8; ct++) partA[w][ct * 16 + m] = m2[ct];
        }
    }
    __syncthreads();   // B3: partA(l2 colmax) ready

    if (tid < 128) {
        float v = fmaxf(fmaxf(partA[0][tid], partA[1][tid]),
                        fmaxf(partA[2][tid], partA[3][tid]));
        Ph[(size_t)blk * 128 + tid] = v;
    }
}

// ---------------------------------------------------------------------------
// vn_attn: ONE BLOCK PER BATCH, 1024 threads (16 waves) -- unchanged from r7.
// ---------------------------------------------------------------------------
__global__ __launch_bounds__(1024) void vn_attn(
    const float* __restrict__ data, const float* __restrict__ Ph,
    const float* __restrict__ Wqf, const float* __restrict__ WkfT,
    const float* __restrict__ bq,
    const float* __restrict__ Wvf, const float* __restrict__ bv,
    float* __restrict__ out)
{
    extern __shared__ float shPh[];                 // [256][129] = 132096 B
    __shared__ __align__(16) float qs[256], tts[128], att[256], pb[128], sc[256];
    __shared__ __align__(16) float part[1024];
    __shared__ float red[8];
    const int b = blockIdx.x, tid = threadIdx.x;
    const float* PhB = Ph + (size_t)b * NPOLY * 128;
    const int agent = (int)data[(size_t)b * NV * LCH];

    // stage PhB -> shPh (pitch 129), coalesced float4 reads
    {
        const float4* src = (const float4*)PhB;
        #pragma unroll
        for (int it = 0; it < 8; it++) {
            int idx4 = it * 1024 + tid;             // 8192 float4 total
            float4 v = src[idx4];
            int lin = idx4 * 4;
            int p = lin >> 7, c = lin & 127;
            float* dst = shPh + p * 129 + c;
            dst[0] = v.x; dst[1] = v.y; dst[2] = v.z; dst[3] = v.w;
        }
    }
    __syncthreads();

    // q partials: thread (c = tid&255, ig = tid>>8) covers i = ig*32..+31
    {
        const int c = tid & 255, ig = tid >> 8;
        const float* pa = shPh + agent * 129 + ig * 32;
        const float* wq = Wqf + (size_t)(ig * 32) * 256 + c;
        float s0 = 0.f, s1 = 0.f, s2 = 0.f, s3 = 0.f;
        #pragma unroll
        for (int i = 0; i < 32; i += 4) {
            s0 = fmaf(pa[i],     wq[(i)     * 256], s0);
            s1 = fmaf(pa[i + 1], wq[(i + 1) * 256], s1);
            s2 = fmaf(pa[i + 2], wq[(i + 2) * 256], s2);
            s3 = fmaf(pa[i + 3], wq[(i + 3) * 256], s3);
        }
        part[ig * 256 + c] = (s0 + s1) + (s2 + s3);
    }
    __syncthreads();
    if (tid < 256)
        qs[tid] = bq[tid] + ((part[tid] + part[256 + tid]) + (part[512 + tid] + part[768 + tid]));
    __syncthreads();

    // tts partials: thread (j = tid&127, cg = tid>>7) covers c = cg*32..+31
    {
        const int j = tid & 127, cg = tid >> 7;
        const float* wk = WkfT + (size_t)(cg * 32) * 128 + j;
        const float* qp = qs + cg * 32;
        float s0 = 0.f, s1 = 0.f, s2 = 0.f, s3 = 0.f;
        #pragma unroll
        for (int c = 0; c < 32; c += 4) {
            s0 = fmaf(qp[c],     wk[(c)     * 128], s0);
            s1 = fmaf(qp[c + 1], wk[(c + 1) * 128], s1);
            s2 = fmaf(qp[c + 2], wk[(c + 2) * 128], s2);
            s3 = fmaf(qp[c + 3], wk[(c + 3) * 128], s3);
        }
        part[cg * 128 + j] = (s0 + s1) + (s2 + s3);
    }
    __syncthreads();
    if (tid < 128) {
        float s = 0.f;
        #pragma unroll
        for (int k = 0; k < 8; k++) s += part[k * 128 + tid];
        tts[tid] = s;
    }
    __syncthreads();

    // score partials: thread (p = tid&255, jg = tid>>8) covers j = jg*32..+31
    {
        const int p = tid & 255, jg = tid >> 8;
        const float* prl = shPh + p * 129 + jg * 32;
        const float* tp = tts + jg * 32;
        float s0 = 0.f, s1 = 0.f, s2 = 0.f, s3 = 0.f;
        #pragma unroll
        for (int j = 0; j < 32; j += 4) {
            s0 = fmaf(prl[j],     tp[j],     s0);
            s1 = fmaf(prl[j + 1], tp[j + 1], s1);
            s2 = fmaf(prl[j + 2], tp[j + 2], s2);
            s3 = fmaf(prl[j + 3], tp[j + 3], s3);
        }
        part[jg * 256 + p] = (s0 + s1) + (s2 + s3);
    }
    __syncthreads();
    if (tid < 256)
        sc[tid] = ((part[tid] + part[256 + tid]) + (part[512 + tid] + part[768 + tid])) * 0.0625f;
    __syncthreads();

    // softmax over 256 scores (waves 0-3 own writes; others compute redundantly)
    float svv = sc[tid & 255];
    float mx = svv;
    #pragma unroll
    for (int s = 1; s < 64; s <<= 1) mx = fmaxf(mx, __shfl_xor(mx, s, 64));
    if (tid < 256 && (tid & 63) == 0) red[tid >> 6] = mx;
    __syncthreads();
    mx = fmaxf(fmaxf(red[0], red[1]), fmaxf(red[2], red[3]));
    float e = expf(svv - mx);
    float sm = e;
    #pragma unroll
    for (int s = 1; s < 64; s <<= 1) sm += __shfl_xor(sm, s, 64);
    if (tid < 256 && (tid & 63) == 0) red[4 + (tid >> 6)] = sm;
    __syncthreads();
    {
        const float tot = red[4] + red[5] + red[6] + red[7];
        if (tid < 256) att[tid] = e / tot;
    }
    __syncthreads();

    // pb partials: thread (c = tid&127, pg = tid>>7) covers p = pg*32..+31
    {
        const int c = tid & 127, pg = tid >> 7;
        const float* ap = att + pg * 32;
        const float* pp = shPh + (size_t)(pg * 32) * 129 + c;
        float s0 = 0.f, s1 = 0.f, s2 = 0.f, s3 = 0.f;
        #pragma unroll
        for (int p = 0; p < 32; p += 4) {
            s0 = fmaf(ap[p],     pp[(p)     * 129], s0);
            s1 = fmaf(ap[p + 1], pp[(p + 1) * 129], s1);
            s2 = fmaf(ap[p + 2], pp[(p + 2) * 129], s2);
            s3 = fmaf(ap[p + 3], pp[(p + 3) * 129], s3);
        }
        part[pg * 128 + c] = (s0 + s1) + (s2 + s3);
    }
    __syncthreads();
    if (tid < 128) {
        float s = 0.f;
        #pragma unroll
        for (int k = 0; k < 8; k++) s += part[k * 128 + tid];
        pb[tid] = s;
    }
    __syncthreads();

    // out partials: thread (c = tid&255, jg = tid>>8) covers j = jg*32..+31
    {
        const int c = tid & 255, jg = tid >> 8;
        const float* wv = Wvf + (size_t)(jg * 32) * 256 + c;
        const float* pbp = pb + jg * 32;
        float s0 = 0.f, s1 = 0.f, s2 = 0.f, s3 = 0.f;
        #pragma unroll
        for (int j = 0; j < 32; j += 4) {
            s0 = fmaf(pbp[j],     wv[(j)     * 256], s0);
            s1 = fmaf(pbp[j + 1], wv[(j + 1) * 256], s1);
            s2 = fmaf(pbp[j + 2], wv[(j + 2) * 256], s2);
            s3 = fmaf(pbp[j + 3], wv[(j + 3) * 256], s3);
        }
        part[jg * 256 + c] = (s0 + s1) + (s2 + s3);
    }
    __syncthreads();
    if (tid < 256)
        out[(size_t)b * 256 + tid] =
            bv[tid] + ((part[tid] + part[256 + tid]) + (part[512 + tid] + part[768 + tid]));
}

extern "C" void kernel_launch(void* const* d_in, const int* in_sizes, int n_in,
                              void* d_out, int out_size, void* d_ws, size_t ws_size,
                              hipStream_t stream)
{
    const float* data = (const float*)d_in[0];
    const float* W0 = (const float*)d_in[1];
    const float* b0 = (const float*)d_in[2];
    const float* g0 = (const float*)d_in[3];
    const float* be0= (const float*)d_in[4];
    const float* W1 = (const float*)d_in[5];
    const float* b1 = (const float*)d_in[6];
    const float* g1 = (const float*)d_in[7];
    const float* be1= (const float*)d_in[8];
    const float* W2 = (const float*)d_in[9];
    const float* b2 = (const float*)d_in[10];
    const float* g2 = (const float*)d_in[11];
    const float* be2= (const float*)d_in[12];
    const float* Wq = (const float*)d_in[13];
    const float* bq = (const float*)d_in[14];
    const float* Wk = (const float*)d_in[15];
    const float* bk = (const float*)d_in[16];
    const float* Wv = (const float*)d_in[17];
    const float* bv = (const float*)d_in[18];
    (void)bk;

    char* wsb = (char*)d_ws;
    float* Ph    = (float*)(wsb);                  // 4 MB
    float* Wqf   = (float*)(wsb + 4194304);        // 128 KB
    float* WkfT  = (float*)(wsb + 4325376);        // 128 KB
    float* Wvf   = (float*)(wsb + 4456448);        // 128 KB
    uint4* wpack = (uint4*)(wsb + 4653568);        // 42 KB

    static int attn_attr_set = 0;
    if (!attn_attr_set) {
        hipFuncSetAttribute((const void*)vn_attn,
                            hipFuncAttributeMaxDynamicSharedMemorySize, 132096);
        attn_attr_set = 1;
    }

    // total prep threads: 3*32768 + 42*64 = 101, - exactly 100992 -> 395 blocks
    vn_prep<<<395, 256, 0, stream>>>(W0, W1, W2, Wq, Wk, Wv, Wvf, Wqf, WkfT, wpack);
    vn_mlp<<<32 * NPOLY, 256, 0, stream>>>(data, wpack,
                                           b0, g0, be0,
                                           b1, g1, be1,
                                           b2, g2, be2, Ph);
    vn_attn<<<32, 1024, 132096, stream>>>(data, Ph, Wqf, WkfT, bq, Wvf, bv, (float*)d_out);
}

// Round 9
// 188.525 us; speedup vs baseline: 1.0621x; 1.0621x over previous
//
#include <hip/hip_runtime.h>

#define NPOLY 256
#define VPP   64
#define LCH   32
#define NV    (1 + NPOLY * VPP)
#define LN_EPS 1e-5f

typedef __bf16 bf16x8 __attribute__((ext_vector_type(8)));
typedef float  f32x4  __attribute__((ext_vector_type(4)));

union U4B8 { uint4 u; bf16x8 v; };

// hardware RNE pack: lo=bf16(a), hi=bf16(b)
__device__ __forceinline__ unsigned packbf(float a, float b) {
    unsigned r;
    asm("v_cvt_pk_bf16_f32 %0, %1, %2" : "=v"(r) : "v"(a), "v"(b));
    return r;
}

// DPP cross-lane term (VALU-only, fuses to v_add_f32_dpp; no DS op, no lgkmcnt)
#define DPPF(x, ctrl) __int_as_float(__builtin_amdgcn_update_dpp(0, __float_as_int(x), (ctrl), 0xF, 0xF, true))

// 16-lane butterfly sum (bitwise == __shfl_xor 1/2/4/8 tree)
__device__ __forceinline__ float red16sum(float x) {
    x += DPPF(x, 0xB1);
    x += DPPF(x, 0x4E);
    x += DPPF(x, 0x141);
    x += DPPF(x, 0x140);
    return x;
}

// ---------------------------------------------------------------------------
// vn_prep: pure coalesced folds, NO Mff matmul.
// ---------------------------------------------------------------------------
__global__ void vn_prep(const float* __restrict__ W0, const float* __restrict__ W1,
                        const float* __restrict__ W2,
                        const float* __restrict__ Wq, const float* __restrict__ Wk,
                        const float* __restrict__ Wv,
                        float* __restrict__ Wvf, float* __restrict__ Wqf,
                        float* __restrict__ WkfT, uint4* __restrict__ wpack)
{
    int t = blockIdx.x * 256 + threadIdx.x;
    if (t < 32768) {                     // Wv fold
        Wvf[t] = Wv[t] + Wv[t + 32768];
        return;
    }
    t -= 32768;
    if (t < 32768) {                     // Wq fold
        Wqf[t] = Wq[t] + Wq[t + 32768];
        return;
    }
    t -= 32768;
    if (t < 32768) {                     // Wk fold + transpose
        int j = t >> 8, c = t & 255;
        WkfT[c * 128 + j] = Wk[j * 256 + c] + Wk[(j + 128) * 256 + c];
        return;
    }
    t -= 32768;
    if (t < 22 * 64) {                   // wpack
        int f = t >> 6, L = t & 63, q = L >> 4, m = L & 15;
        const float* src; int N, k0, col;
        if (f < 2)      { src = W0; N = 32;  k0 = q * 8;                 col = f * 16 + m; }
        else if (f < 6) { src = W1; N = 64;  k0 = q * 8;                 col = (f - 2) * 16 + m; }
        else { int g = f - 6; src = W2; N = 128; k0 = (g >> 3) * 32 + q * 8; col = (g & 7) * 16 + m; }
        float e[8];
        #pragma unroll
        for (int j = 0; j < 8; j++) e[j] = src[(k0 + j) * N + col];
        uint4 o;
        o.x = packbf(e[0], e[1]); o.y = packbf(e[2], e[3]);
        o.z = packbf(e[4], e[5]); o.w = packbf(e[6], e[7]);
        wpack[f * 64 + L] = o;
    }
}

// ---------------------------------------------------------------------------
// vn_mlp: ONE POLY PER 256-THREAD BLOCK, 4 waves x 16 rows each.
// Round-5 form (best measured). launch_bounds(256,4): VGPR natural ~36,
// 128-cap hint cannot spill; nudges occupancy target up.
// C/D layout (m89): col = lane&15, row = (lane>>4)*4 + reg.
// A layout (m120): A[m = lane&15][k = (lane>>4)*8 + j].
// ---------------------------------------------------------------------------
__global__ __launch_bounds__(256, 4) void vn_mlp(
    const float* __restrict__ data, const uint4* __restrict__ wpack,
    const float* __restrict__ b0, const float* __restrict__ g0, const float* __restrict__ be0,
    const float* __restrict__ W1, const float* __restrict__ b1,
    const float* __restrict__ g1, const float* __restrict__ be1,
    const float* __restrict__ W2, const float* __restrict__ b2,
    const float* __restrict__ g2, const float* __restrict__ be2,
    float* __restrict__ Ph)
{
    __shared__ __align__(16) unsigned short hbuf[64 * 72];  // 9216 B (rows wave-owned)
    __shared__ float partA[4][128];   // per-wave column-max partials
    __shared__ float partB[4][128];   // per-wave au partials

    const int tid = threadIdx.x;
    const int w = tid >> 6, L = tid & 63, q = L >> 4, m = L & 15;
    const int blk = blockIdx.x;
    const int bb = blk >> 8, pp = blk & 255;
    const int r0 = w * 16;            // this wave's row base

    // ---------------- layer 0 : 32 -> 32 (rows r0..r0+15) ----------------
    const float* rowbase = data + ((size_t)bb * NV + 1 + (size_t)pp * VPP) * LCH;
    bf16x8 A0;
    {
        const float* rp = rowbase + (size_t)(r0 + m) * LCH + q * 8;
        float4 u = *(const float4*)rp;
        float4 v = *(const float4*)(rp + 4);
        if (q == 3) v.w = 0.f;                 // vecs[:, :, -1] = 0
        U4B8 c;
        c.u.x = packbf(u.x, u.y); c.u.y = packbf(u.z, u.w);
        c.u.z = packbf(v.x, v.y); c.u.w = packbf(v.z, v.w);
        A0 = c.v;
    }
    f32x4 acc0[2];
    {
        U4B8 t0, t1; t0.u = wpack[0 * 64 + L]; t1.u = wpack[1 * 64 + L];
        float bca = b0[m], bcb = b0[16 + m];
        f32x4 a0 = { bca, bca, bca, bca };
        f32x4 a1 = { bcb, bcb, bcb, bcb };
        acc0[0] = __builtin_amdgcn_mfma_f32_16x16x32_bf16(A0, t0.v, a0, 0, 0, 0);
        acc0[1] = __builtin_amdgcn_mfma_f32_16x16x32_bf16(A0, t1.v, a1, 0, 0, 0);
    }
    // LN (per row, N=32) + relu + wave-partial col-max
    {
        float g0c[2]  = { g0[m],  g0[16 + m]  };
        float be0c[2] = { be0[m], be0[16 + m] };
        float a0mx[2] = { 0.f, 0.f };
        #pragma unroll
        for (int reg = 0; reg < 4; reg++) {
            float x0 = acc0[0][reg], x1 = acc0[1][reg];
            float rs = red16sum(x0 + x1);
            float rq = red16sum(x0 * x0 + x1 * x1);
            float mu = rs * (1.f / 32.f);
            float var = rq * (1.f / 32.f) - mu * mu;
            float ri = rsqrtf(var + LN_EPS);
            #pragma unroll
            for (int ct = 0; ct < 2; ct++) {
                float v = fmaxf(fmaf(g0c[ct] * ri, acc0[ct][reg] - mu, be0c[ct]), 0.f);
                acc0[ct][reg] = v;
                a0mx[ct] = fmaxf(a0mx[ct], v);
            }
        }
        #pragma unroll
        for (int ct = 0; ct < 2; ct++) {
            float v = a0mx[ct];
            v = fmaxf(v, __shfl_xor(v, 16, 64));
            v = fmaxf(v, __shfl_xor(v, 32, 64));
            a0mx[ct] = v;
        }
        if (q == 0) { partA[w][m] = a0mx[0]; partA[w][16 + m] = a0mx[1]; }
    }
    // stage h0 (bf16) for layer-1 A fragments (wave-local rows)
    #pragma unroll
    for (int reg = 0; reg < 4; reg++) {
        int row = r0 + q * 4 + reg;
        unsigned u = packbf(acc0[0][reg], acc0[1][reg]);
        hbuf[row * 72 + m]      = (unsigned short)u;
        hbuf[row * 72 + 16 + m] = (unsigned short)(u >> 16);
    }
    __syncthreads();   // (1) partA ready

    // au1 partial: wave w covers j = w*8 .. w*8+7
    {
        float p = 0.f;
        int j0 = w * 8;
        #pragma unroll
        for (int jj = 0; jj < 8; jj++) {
            int j = j0 + jj;
            float a = fmaxf(fmaxf(partA[0][j], partA[1][j]), fmaxf(partA[2][j], partA[3][j]));
            p = fmaf(a, W1[(32 + j) * 64 + L], p);
        }
        partB[w][L] = p;
    }
    __syncthreads();   // (2) partB(au1) ready

    // ---------------- layer 1 : 64(per-row 32) -> 64 ----------------
    bf16x8 A1;
    { U4B8 c; c.u = *(const uint4*)(hbuf + (r0 + m) * 72 + q * 8); A1 = c.v; }
    f32x4 acc1[4];
    #pragma unroll
    for (int ct = 0; ct < 4; ct++) {
        U4B8 wv; wv.u = wpack[(2 + ct) * 64 + L];
        int n = ct * 16 + m;
        float au = b1[n] + ((partB[0][n] + partB[1][n]) + (partB[2][n] + partB[3][n]));
        f32x4 a = { au, au, au, au };
        acc1[ct] = __builtin_amdgcn_mfma_f32_16x16x32_bf16(A1, wv.v, a, 0, 0, 0);
    }
    {
        float g1c[4], be1c[4];
        #pragma unroll
        for (int ct = 0; ct < 4; ct++) { g1c[ct] = g1[ct * 16 + m]; be1c[ct] = be1[ct * 16 + m]; }
        float a1mx[4] = { 0.f, 0.f, 0.f, 0.f };
        #pragma unroll
        for (int reg = 0; reg < 4; reg++) {
            float rs = 0.f, rq = 0.f;
            #pragma unroll
            for (int ct = 0; ct < 4; ct++) { float x = acc1[ct][reg]; rs += x; rq = fmaf(x, x, rq); }
            rs = red16sum(rs);
            rq = red16sum(rq);
            float mu = rs * (1.f / 64.f);
            float var = rq * (1.f / 64.f) - mu * mu;
            float ri = rsqrtf(var + LN_EPS);
            #pragma unroll
            for (int ct = 0; ct < 4; ct++) {
                float v = fmaxf(fmaf(g1c[ct] * ri, acc1[ct][reg] - mu, be1c[ct]), 0.f);
                acc1[ct][reg] = v;
                a1mx[ct] = fmaxf(a1mx[ct], v);
            }
        }
        #pragma unroll
        for (int ct = 0; ct < 4; ct++) {
            float v = a1mx[ct];
            v = fmaxf(v, __shfl_xor(v, 16, 64));
            v = fmaxf(v, __shfl_xor(v, 32, 64));
            a1mx[ct] = v;
        }
        if (q == 0) {
            #pragma unroll
            for (int ct = 0; ct < 4; ct++) partA[w][ct * 16 + m] = a1mx[ct];
        }
    }
    // stage h1 (bf16), wave-local rows
    #pragma unroll
    for (int reg = 0; reg < 4; reg++) {
        int row = r0 + q * 4 + reg;
        unsigned ua = packbf(acc1[0][reg], acc1[1][reg]);
        unsigned ub = packbf(acc1[2][reg], acc1[3][reg]);
        hbuf[row * 72 + m]      = (unsigned short)ua;
        hbuf[row * 72 + 16 + m] = (unsigned short)(ua >> 16);
        hbuf[row * 72 + 32 + m] = (unsigned short)ub;
        hbuf[row * 72 + 48 + m] = (unsigned short)(ub >> 16);
    }
    __syncthreads();   // (3) partA(l1 colmax) ready

    // au2 partial: wave w covers j = w*16 .. w*16+15; outputs cols L and 64+L
    {
        float pa = 0.f, pb = 0.f;
        int j0 = w * 16;
        #pragma unroll
        for (int jj = 0; jj < 16; jj++) {
            int j = j0 + jj;
            float a = fmaxf(fmaxf(partA[0][j], partA[1][j]), fmaxf(partA[2][j], partA[3][j]));
            pa = fmaf(a, W2[(64 + j) * 128 + L],      pa);
            pb = fmaf(a, W2[(64 + j) * 128 + 64 + L], pb);
        }
        partB[w][L]      = pa;
        partB[w][64 + L] = pb;
    }
    __syncthreads();   // (4) partB(au2) ready

    // ---------------- layer 2 : 128(per-row 64) -> 128, single pass ----------------
    bf16x8 A2[2];
    #pragma unroll
    for (int ks = 0; ks < 2; ks++) {
        U4B8 c; c.u = *(const uint4*)(hbuf + (r0 + m) * 72 + ks * 32 + q * 8);
        A2[ks] = c.v;
    }
    f32x4 acc2[8];
    #pragma unroll
    for (int ct = 0; ct < 8; ct++) {
        U4B8 wa, wb;
        wa.u = wpack[(6 + ct) * 64 + L];
        wb.u = wpack[(14 + ct) * 64 + L];
        int n = ct * 16 + m;
        float au = b2[n] + ((partB[0][n] + partB[1][n]) + (partB[2][n] + partB[3][n]));
        f32x4 a = { au, au, au, au };
        a = __builtin_amdgcn_mfma_f32_16x16x32_bf16(A2[0], wa.v, a, 0, 0, 0);
        a = __builtin_amdgcn_mfma_f32_16x16x32_bf16(A2[1], wb.v, a, 0, 0, 0);
        acc2[ct] = a;
    }
    {
        float g2c[8], be2c[8];
        #pragma unroll
        for (int ct = 0; ct < 8; ct++) { g2c[ct] = g2[ct * 16 + m]; be2c[ct] = be2[ct * 16 + m]; }
        float m2[8] = { 0.f, 0.f, 0.f, 0.f, 0.f, 0.f, 0.f, 0.f };
        #pragma unroll
        for (int reg = 0; reg < 4; reg++) {
            float rs = 0.f, rq = 0.f;
            #pragma unroll
            for (int ct = 0; ct < 8; ct++) { float x = acc2[ct][reg]; rs += x; rq = fmaf(x, x, rq); }
            rs = red16sum(rs);
            rq = red16sum(rq);
            float mu = rs * (1.f / 128.f);
            float var = rq * (1.f / 128.f) - mu * mu;
            float ri = rsqrtf(var + LN_EPS);
            #pragma unroll
            for (int ct = 0; ct < 8; ct++) {
                float v = fmaxf(fmaf(g2c[ct] * ri, acc2[ct][reg] - mu, be2c[ct]), 0.f);
                m2[ct] = fmaxf(m2[ct], v);
            }
        }
        #pragma unroll
        for (int ct = 0; ct < 8; ct++) {
            float v = m2[ct];
            v = fmaxf(v, __shfl_xor(v, 16, 64));
            v = fmaxf(v, __shfl_xor(v, 32, 64));
            m2[ct] = v;
        }
        if (q == 0) {
            #pragma unroll
            for (int ct = 0; ct < 8; ct++) partA[w][ct * 16 + m] = m2[ct];
        }
    }
    __syncthreads();   // (5) partA(l2 colmax) ready

    if (tid < 128) {
        float v = fmaxf(fmaxf(partA[0][tid], partA[1][tid]),
                        fmaxf(partA[2][tid], partA[3][tid]));
        Ph[(size_t)blk * 128 + tid] = v;
    }
}

// ---------------------------------------------------------------------------
// vn_attn: ONE BLOCK PER BATCH, 1024 threads (16 waves). Every phase split
// 4-8 ways with LDS partial combines.
// ---------------------------------------------------------------------------
__global__ __launch_bounds__(1024) void vn_attn(
    const float* __restrict__ data, const float* __restrict__ Ph,
    const float* __restrict__ Wqf, const float* __restrict__ WkfT,
    const float* __restrict__ bq,
    const float* __restrict__ Wvf, const float* __restrict__ bv,
    float* __restrict__ out)
{
    extern __shared__ float shPh[];                 // [256][129] = 132096 B
    __shared__ __align__(16) float qs[256], tts[128], att[256], pb[128], sc[256];
    __shared__ __align__(16) float part[1024];
    __shared__ float red[8];
    const int b = blockIdx.x, tid = threadIdx.x;
    const float* PhB = Ph + (size_t)b * NPOLY * 128;
    const int agent = (int)data[(size_t)b * NV * LCH];

    // stage PhB -> shPh (pitch 129), coalesced float4 reads
    {
        const float4* src = (const float4*)PhB;
        #pragma unroll
        for (int it = 0; it < 8; it++) {
            int idx4 = it * 1024 + tid;             // 8192 float4 total
            float4 v = src[idx4];
            int lin = idx4 * 4;
            int p = lin >> 7, c = lin & 127;
            float* dst = shPh + p * 129 + c;
            dst[0] = v.x; dst[1] = v.y; dst[2] = v.z; dst[3] = v.w;
        }
    }
    __syncthreads();

    // q partials: thread (c = tid&255, ig = tid>>8) covers i = ig*32..+31
    {
        const int c = tid & 255, ig = tid >> 8;
        const float* pa = shPh + agent * 129 + ig * 32;
        const float* wq = Wqf + (size_t)(ig * 32) * 256 + c;
        float s0 = 0.f, s1 = 0.f, s2 = 0.f, s3 = 0.f;
        #pragma unroll
        for (int i = 0; i < 32; i += 4) {
            s0 = fmaf(pa[i],     wq[(i)     * 256], s0);
            s1 = fmaf(pa[i + 1], wq[(i + 1) * 256], s1);
            s2 = fmaf(pa[i + 2], wq[(i + 2) * 256], s2);
            s3 = fmaf(pa[i + 3], wq[(i + 3) * 256], s3);
        }
        part[ig * 256 + c] = (s0 + s1) + (s2 + s3);
    }
    __syncthreads();
    if (tid < 256)
        qs[tid] = bq[tid] + ((part[tid] + part[256 + tid]) + (part[512 + tid] + part[768 + tid]));
    __syncthreads();

    // tts partials: thread (j = tid&127, cg = tid>>7) covers c = cg*32..+31
    {
        const int j = tid & 127, cg = tid >> 7;
        const float* wk = WkfT + (size_t)(cg * 32) * 128 + j;
        const float* qp = qs + cg * 32;
        float s0 = 0.f, s1 = 0.f, s2 = 0.f, s3 = 0.f;
        #pragma unroll
        for (int c = 0; c < 32; c += 4) {
            s0 = fmaf(qp[c],     wk[(c)     * 128], s0);
            s1 = fmaf(qp[c + 1], wk[(c + 1) * 128], s1);
            s2 = fmaf(qp[c + 2], wk[(c + 2) * 128], s2);
            s3 = fmaf(qp[c + 3], wk[(c + 3) * 128], s3);
        }
        part[cg * 128 + j] = (s0 + s1) + (s2 + s3);
    }
    __syncthreads();
    if (tid < 128) {
        float s = 0.f;
        #pragma unroll
        for (int k = 0; k < 8; k++) s += part[k * 128 + tid];
        tts[tid] = s;
    }
    __syncthreads();

    // score partials: thread (p = tid&255, jg = tid>>8) covers j = jg*32..+31
    {
        const int p = tid & 255, jg = tid >> 8;
        const float* prl = shPh + p * 129 + jg * 32;
        const float* tp = tts + jg * 32;
        float s0 = 0.f, s1 = 0.f, s2 = 0.f, s3 = 0.f;
        #pragma unroll
        for (int j = 0; j < 32; j += 4) {
            s0 = fmaf(prl[j],     tp[j],     s0);
            s1 = fmaf(prl[j + 1], tp[j + 1], s1);
            s2 = fmaf(prl[j + 2], tp[j + 2], s2);
            s3 = fmaf(prl[j + 3], tp[j + 3], s3);
        }
        part[jg * 256 + p] = (s0 + s1) + (s2 + s3);
    }
    __syncthreads();
    if (tid < 256)
        sc[tid] = ((part[tid] + part[256 + tid]) + (part[512 + tid] + part[768 + tid])) * 0.0625f;
    __syncthreads();

    // softmax over 256 scores (waves 0-3 own writes; others compute redundantly)
    float svv = sc[tid & 255];
    float mx = svv;
    #pragma unroll
    for (int s = 1; s < 64; s <<= 1) mx = fmaxf(mx, __shfl_xor(mx, s, 64));
    if (tid < 256 && (tid & 63) == 0) red[tid >> 6] = mx;
    __syncthreads();
    mx = fmaxf(fmaxf(red[0], red[1]), fmaxf(red[2], red[3]));
    float e = expf(svv - mx);
    float sm = e;
    #pragma unroll
    for (int s = 1; s < 64; s <<= 1) sm += __shfl_xor(sm, s, 64);
    if (tid < 256 && (tid & 63) == 0) red[4 + (tid >> 6)] = sm;
    __syncthreads();
    {
        const float tot = red[4] + red[5] + red[6] + red[7];
        if (tid < 256) att[tid] = e / tot;
    }
    __syncthreads();

    // pb partials: thread (c = tid&127, pg = tid>>7) covers p = pg*32..+31
    {
        const int c = tid & 127, pg = tid >> 7;
        const float* ap = att + pg * 32;
        const float* pp = shPh + (size_t)(pg * 32) * 129 + c;
        float s0 = 0.f, s1 = 0.f, s2 = 0.f, s3 = 0.f;
        #pragma unroll
        for (int p = 0; p < 32; p += 4) {
            s0 = fmaf(ap[p],     pp[(p)     * 129], s0);
            s1 = fmaf(ap[p + 1], pp[(p + 1) * 129], s1);
            s2 = fmaf(ap[p + 2], pp[(p + 2) * 129], s2);
            s3 = fmaf(ap[p + 3], pp[(p + 3) * 129], s3);
        }
        part[pg * 128 + c] = (s0 + s1) + (s2 + s3);
    }
    __syncthreads();
    if (tid < 128) {
        float s = 0.f;
        #pragma unroll
        for (int k = 0; k < 8; k++) s += part[k * 128 + tid];
        pb[tid] = s;
    }
    __syncthreads();

    // out partials: thread (c = tid&255, jg = tid>>8) covers j = jg*32..+31
    {
        const int c = tid & 255, jg = tid >> 8;
        const float* wv = Wvf + (size_t)(jg * 32) * 256 + c;
        const float* pbp = pb + jg * 32;
        float s0 = 0.f, s1 = 0.f, s2 = 0.f, s3 = 0.f;
        #pragma unroll
        for (int j = 0; j < 32; j += 4) {
            s0 = fmaf(pbp[j],     wv[(j)     * 256], s0);
            s1 = fmaf(pbp[j + 1], wv[(j + 1) * 256], s1);
            s2 = fmaf(pbp[j + 2], wv[(j + 2) * 256], s2);
            s3 = fmaf(pbp[j + 3], wv[(j + 3) * 256], s3);
        }
        part[jg * 256 + c] = (s0 + s1) + (s2 + s3);
    }
    __syncthreads();
    if (tid < 256)
        out[(size_t)b * 256 + tid] =
            bv[tid] + ((part[tid] + part[256 + tid]) + (part[512 + tid] + part[768 + tid]));
}

extern "C" void kernel_launch(void* const* d_in, const int* in_sizes, int n_in,
                              void* d_out, int out_size, void* d_ws, size_t ws_size,
                              hipStream_t stream)
{
    const float* data = (const float*)d_in[0];
    const float* W0 = (const float*)d_in[1];
    const float* b0 = (const float*)d_in[2];
    const float* g0 = (const float*)d_in[3];
    const float* be0= (const float*)d_in[4];
    const float* W1 = (const float*)d_in[5];
    const float* b1 = (const float*)d_in[6];
    const float* g1 = (const float*)d_in[7];
    const float* be1= (const float*)d_in[8];
    const float* W2 = (const float*)d_in[9];
    const float* b2 = (const float*)d_in[10];
    const float* g2 = (const float*)d_in[11];
    const float* be2= (const float*)d_in[12];
    const float* Wq = (const float*)d_in[13];
    const float* bq = (const float*)d_in[14];
    const float* Wk = (const float*)d_in[15];
    const float* bk = (const float*)d_in[16];
    const float* Wv = (const float*)d_in[17];
    const float* bv = (const float*)d_in[18];
    (void)bk;

    char* wsb = (char*)d_ws;
    float* Ph    = (float*)(wsb);                  // 4 MB
    float* Wqf   = (float*)(wsb + 4194304);        // 128 KB
    float* WkfT  = (float*)(wsb + 4325376);        // 128 KB
    float* Wvf   = (float*)(wsb + 4456448);        // 128 KB
    uint4* wpack = (uint4*)(wsb + 4653568);        // 22 KB

    static int attn_attr_set = 0;
    if (!attn_attr_set) {
        hipFuncSetAttribute((const void*)vn_attn,
                            hipFuncAttributeMaxDynamicSharedMemorySize, 132096);
        attn_attr_set = 1;
    }

    vn_prep<<<390, 256, 0, stream>>>(W0, W1, W2, Wq, Wk, Wv, Wvf, Wqf, WkfT, wpack);
    vn_mlp<<<32 * NPOLY, 256, 0, stream>>>(data, wpack,
                                           b0, g0, be0,
                                           W1, b1, g1, be1,
                                           W2, b2, g2, be2, Ph);
    vn_attn<<<32, 1024, 132096, stream>>>(data, Ph, Wqf, WkfT, bq, Wvf, bv, (float*)d_out);
}